// Round 1
// baseline (8345.239 us; speedup 1.0000x reference)
//
#include <hip/hip_runtime.h>
#include <hip/hip_bf16.h>

#define VV 32000
#define EE 256
#define HH 512
#define BB 64
#define TT 64
#define SS 64
#define G3 1536   // 3*H

typedef __attribute__((ext_vector_type(8))) short bf16x8;
typedef __attribute__((ext_vector_type(4))) float f32x4;

__device__ __forceinline__ void async16(void* lds, const void* g) {
  __builtin_amdgcn_global_load_lds((const __attribute__((address_space(1))) void*)g,
                                   (__attribute__((address_space(3))) void*)lds, 16, 0, 0);
}

__device__ __forceinline__ float sigmoidf_(float x) { return 1.0f / (1.0f + expf(-x)); }

// ---------------- generic 2D transpose: dst[C][R] = src[R][C]^T (R,C multiples of 32)
__global__ __launch_bounds__(256) void transpose_kernel(float* __restrict__ dst,
                                                        const float* __restrict__ src,
                                                        int R, int C) {
  __shared__ float tile[32][33];
  int c0 = blockIdx.x * 32, r0 = blockIdx.y * 32;
  int x = threadIdx.x, y = threadIdx.y;     // block (32,8)
  for (int i = y; i < 32; i += 8) tile[i][x] = src[(size_t)(r0 + i) * C + c0 + x];
  __syncthreads();
  for (int i = y; i < 32; i += 8) dst[(size_t)(c0 + i) * R + r0 + x] = tile[x][i];
}

// ---------------- fp32 -> bf16 cast
__global__ __launch_bounds__(256) void cast_kernel(const float* __restrict__ src,
                                                   __hip_bfloat16* __restrict__ dst, int n) {
  for (int i = blockIdx.x * blockDim.x + threadIdx.x; i < n; i += gridDim.x * blockDim.x)
    dst[i] = __float2bfloat16(src[i]);
}

// ---------------- keys_proj[b,s,n] = sum_h enc[b,s,h] * WkT[h][n]
__global__ __launch_bounds__(256) void keys_kernel(const float* __restrict__ enc,
                                                   const float* __restrict__ WkT,
                                                   float* __restrict__ keysp) {
  __shared__ float row[HH];
  int m = blockIdx.x;          // b*S + s
  int tid = threadIdx.x;
  row[tid] = enc[(size_t)m * HH + tid];
  row[tid + 256] = enc[(size_t)m * HH + tid + 256];
  __syncthreads();
  float a0 = 0.f, a1 = 0.f;
#pragma unroll 8
  for (int h = 0; h < HH; ++h) {
    const float* wr = WkT + (size_t)h * HH;
    float x = row[h];
    a0 += wr[tid] * x;
    a1 += wr[tid + 256] * x;
  }
  keysp[(size_t)m * HH + tid] = a0;
  keysp[(size_t)m * HH + tid + 256] = a1;
}

// ---------------- gix[t*B+b][n] = b_ih0[n] + sum_e emb[X[b,t]][e] * WT0[512+e][n]
__global__ __launch_bounds__(256) void gix_kernel(const int* __restrict__ X,
                                                  const float* __restrict__ emb,
                                                  const float* __restrict__ WT0,
                                                  const float* __restrict__ b_ih0,
                                                  float* __restrict__ gix) {
  __shared__ float xr[EE];
  int m = blockIdx.x;          // t*B + b
  int t = m >> 6, b = m & 63;
  int tid = threadIdx.x;
  int tok = X[b * TT + t];
  xr[tid] = emb[(size_t)tok * EE + tid];
  __syncthreads();
  const float* WX = WT0 + (size_t)HH * G3;
  float acc[6];
#pragma unroll
  for (int i = 0; i < 6; ++i) acc[i] = b_ih0[tid + i * 256];
#pragma unroll 4
  for (int e = 0; e < EE; ++e) {
    float x = xr[e];
    const float* wr = WX + (size_t)e * G3;
#pragma unroll
    for (int i = 0; i < 6; ++i) acc[i] += wr[tid + i * 256] * x;
  }
#pragma unroll
  for (int i = 0; i < 6; ++i) gix[(size_t)m * G3 + tid + i * 256] = acc[i];
}

// ---------------- per-step attention: q = h1 @ Wq^T ; scores ; softmax ; context
__global__ __launch_bounds__(512) void attn_kernel(const float* __restrict__ h1_in,
                                                   const float* __restrict__ WqT,
                                                   const float* __restrict__ keysp,
                                                   const float* __restrict__ enc,
                                                   const float* __restrict__ wv,
                                                   const int* __restrict__ vlen,
                                                   float* __restrict__ context) {
  __shared__ float h1s[HH], qs[HH], wvs[HH], attns[SS];
  int b = blockIdx.x;
  int tid = threadIdx.x;
  h1s[tid] = h1_in[b * HH + tid];
  wvs[tid] = wv[tid];
  __syncthreads();
  // q[tid]
  float acc = 0.f;
#pragma unroll 8
  for (int h = 0; h < HH; ++h) acc += WqT[(size_t)h * HH + tid] * h1s[h];
  qs[tid] = acc;
  __syncthreads();
  // scores: wave w handles s = w, w+8, ...
  int w = tid >> 6, lane = tid & 63;
  int vl = vlen[b];
  for (int s = w; s < SS; s += 8) {
    const float* kp = keysp + (size_t)(b * SS + s) * HH;
    float p = 0.f;
#pragma unroll
    for (int h = lane; h < HH; h += 64) p += tanhf(qs[h] + kp[h]) * wvs[h];
    for (int off = 32; off > 0; off >>= 1) p += __shfl_down(p, off);
    if (lane == 0) attns[s] = (s < vl) ? p : -1e6f;
  }
  __syncthreads();
  // softmax over 64 by wave 0
  if (w == 0) {
    float v = attns[lane];
    float mx = v;
    for (int off = 32; off > 0; off >>= 1) mx = fmaxf(mx, __shfl_xor(mx, off));
    float e = expf(v - mx);
    float sm = e;
    for (int off = 32; off > 0; off >>= 1) sm += __shfl_xor(sm, off);
    attns[lane] = e / sm;
  }
  __syncthreads();
  // context[tid]
  float c = 0.f;
#pragma unroll 4
  for (int s = 0; s < SS; ++s) c += attns[s] * enc[(size_t)(b * SS + s) * HH + tid];
  context[b * HH + tid] = c;
}

// ---------------- per-step GRU layer 0 (ctx part live, x part precomputed in gix)
__global__ __launch_bounds__(256) void gru0_kernel(const float* __restrict__ context,
                                                   const float* __restrict__ h0_in,
                                                   const float* __restrict__ WT0,   // [768][1536], rows 0..511 = ctx part
                                                   const float* __restrict__ WTh0,  // [512][1536]
                                                   const float* __restrict__ gix,
                                                   const float* __restrict__ b_hh0,
                                                   float* __restrict__ h0_out, int t) {
  __shared__ float ctx[HH], h0s[HH];
  __shared__ float red[6][2][128];
  int bi = blockIdx.x;
  int b = bi >> 2, js = bi & 3;
  int tid = threadIdx.x;
  ctx[tid] = context[b * HH + tid];
  ctx[tid + 256] = context[b * HH + tid + 256];
  h0s[tid] = h0_in[b * HH + tid];
  h0s[tid + 256] = h0_in[b * HH + tid + 256];
  __syncthreads();
  int jj = tid & 127, kh = tid >> 7;
  int j = js * 128 + jj;
  int k0 = kh * 256;
  float gr = 0, gz = 0, gn = 0, hr = 0, hz = 0, hn = 0;
#pragma unroll 4
  for (int k = k0; k < k0 + 256; ++k) {
    float c = ctx[k], h = h0s[k];
    const float* wi = WT0 + (size_t)k * G3 + j;
    const float* wh = WTh0 + (size_t)k * G3 + j;
    gr += wi[0] * c;    gz += wi[512] * c;   gn += wi[1024] * c;
    hr += wh[0] * h;    hz += wh[512] * h;   hn += wh[1024] * h;
  }
  red[0][kh][jj] = gr; red[1][kh][jj] = gz; red[2][kh][jj] = gn;
  red[3][kh][jj] = hr; red[4][kh][jj] = hz; red[5][kh][jj] = hn;
  __syncthreads();
  if (kh == 0) {
    float Gr = red[0][0][jj] + red[0][1][jj];
    float Gz = red[1][0][jj] + red[1][1][jj];
    float Gn = red[2][0][jj] + red[2][1][jj];
    float Hr = red[3][0][jj] + red[3][1][jj];
    float Hz = red[4][0][jj] + red[4][1][jj];
    float Hn = red[5][0][jj] + red[5][1][jj];
    const float* gx = gix + (size_t)(t * BB + b) * G3;
    float i_r = gx[j] + Gr, i_z = gx[j + 512] + Gz, i_n = gx[j + 1024] + Gn;
    float h_r = b_hh0[j] + Hr, h_z = b_hh0[j + 512] + Hz, h_n = b_hh0[j + 1024] + Hn;
    float r = sigmoidf_(i_r + h_r);
    float z = sigmoidf_(i_z + h_z);
    float n = tanhf(i_n + r * h_n);
    h0_out[b * HH + j] = (1.f - z) * n + z * h0s[j];
  }
}

// ---------------- per-step GRU layer 1 (also emits bf16 outs row)
__global__ __launch_bounds__(256) void gru1_kernel(const float* __restrict__ h0_new,
                                                   const float* __restrict__ h1_in,
                                                   const float* __restrict__ WT1,   // [512][1536]
                                                   const float* __restrict__ WTh1,  // [512][1536]
                                                   const float* __restrict__ b_ih1,
                                                   const float* __restrict__ b_hh1,
                                                   float* __restrict__ h1_out,
                                                   __hip_bfloat16* __restrict__ outsb, int t) {
  __shared__ float xs[HH], h1s[HH];
  __shared__ float red[6][2][128];
  int bi = blockIdx.x;
  int b = bi >> 2, js = bi & 3;
  int tid = threadIdx.x;
  xs[tid] = h0_new[b * HH + tid];
  xs[tid + 256] = h0_new[b * HH + tid + 256];
  h1s[tid] = h1_in[b * HH + tid];
  h1s[tid + 256] = h1_in[b * HH + tid + 256];
  __syncthreads();
  int jj = tid & 127, kh = tid >> 7;
  int j = js * 128 + jj;
  int k0 = kh * 256;
  float gr = 0, gz = 0, gn = 0, hr = 0, hz = 0, hn = 0;
#pragma unroll 4
  for (int k = k0; k < k0 + 256; ++k) {
    float x = xs[k], h = h1s[k];
    const float* wi = WT1 + (size_t)k * G3 + j;
    const float* wh = WTh1 + (size_t)k * G3 + j;
    gr += wi[0] * x;    gz += wi[512] * x;   gn += wi[1024] * x;
    hr += wh[0] * h;    hz += wh[512] * h;   hn += wh[1024] * h;
  }
  red[0][kh][jj] = gr; red[1][kh][jj] = gz; red[2][kh][jj] = gn;
  red[3][kh][jj] = hr; red[4][kh][jj] = hz; red[5][kh][jj] = hn;
  __syncthreads();
  if (kh == 0) {
    float Gr = red[0][0][jj] + red[0][1][jj];
    float Gz = red[1][0][jj] + red[1][1][jj];
    float Gn = red[2][0][jj] + red[2][1][jj];
    float Hr = red[3][0][jj] + red[3][1][jj];
    float Hz = red[4][0][jj] + red[4][1][jj];
    float Hn = red[5][0][jj] + red[5][1][jj];
    float i_r = b_ih1[j] + Gr, i_z = b_ih1[j + 512] + Gz, i_n = b_ih1[j + 1024] + Gn;
    float h_r = b_hh1[j] + Hr, h_z = b_hh1[j + 512] + Hz, h_n = b_hh1[j + 1024] + Hn;
    float r = sigmoidf_(i_r + h_r);
    float z = sigmoidf_(i_z + h_z);
    float n = tanhf(i_n + r * h_n);
    float hv = (1.f - z) * n + z * h1s[j];
    h1_out[b * HH + j] = hv;
    outsb[(size_t)(t * BB + b) * HH + j] = __float2bfloat16(hv);
  }
}

// ---------------- final dense: C[m,v] = A[m,:] . Bt[v,:] + bias[v], scatter to [B,T,V]
// m97-style 128x128 tile, bf16 MFMA 16x16x32, global_load_lds width 16
__global__ __launch_bounds__(256) void dense_kernel(const __hip_bfloat16* __restrict__ A,
                                                    const __hip_bfloat16* __restrict__ Bt,
                                                    const float* __restrict__ bias,
                                                    float* __restrict__ out) {
  __shared__ __align__(16) short As[128 * 64];
  __shared__ __align__(16) short Bs[128 * 64];
  int mt = blockIdx.x;         // 0..31
  int nt = blockIdx.y;         // 0..249
  int tid = threadIdx.x;
  int w = tid >> 6, lane = tid & 63;
  int wm = w >> 1, wn = w & 1;
  f32x4 acc[4][4];
#pragma unroll
  for (int m = 0; m < 4; ++m)
#pragma unroll
    for (int n = 0; n < 4; ++n) acc[m][n] = (f32x4)0.f;

  const short* Ag = (const short*)A + (size_t)(mt * 128) * 512;
  const short* Bg = (const short*)Bt + (size_t)(nt * 128) * 512;

  for (int kt = 0; kt < 8; ++kt) {
    int k0 = kt * 64;
#pragma unroll
    for (int c = 0; c < 4; ++c) {
      int chunk = w * 4 + c;                  // 0..15, wave-uniform
      int row = chunk * 8 + (lane >> 3);      // 0..127
      int col = (lane & 7) * 8;               // bf16 col within 64
      async16(As + chunk * 512, Ag + (size_t)row * 512 + k0 + col);
      async16(Bs + chunk * 512, Bg + (size_t)row * 512 + k0 + col);
    }
    __syncthreads();
#pragma unroll
    for (int kk = 0; kk < 2; ++kk) {
      int krow = kk * 32 + (lane >> 4) * 8;
      bf16x8 af[4], bf[4];
#pragma unroll
      for (int m = 0; m < 4; ++m) {
        int r = wm * 64 + m * 16 + (lane & 15);
        af[m] = *(const bf16x8*)&As[r * 64 + krow];
      }
#pragma unroll
      for (int n = 0; n < 4; ++n) {
        int r = wn * 64 + n * 16 + (lane & 15);
        bf[n] = *(const bf16x8*)&Bs[r * 64 + krow];
      }
#pragma unroll
      for (int m = 0; m < 4; ++m)
#pragma unroll
        for (int n = 0; n < 4; ++n)
          acc[m][n] = __builtin_amdgcn_mfma_f32_16x16x32_bf16(af[m], bf[n], acc[m][n], 0, 0, 0);
    }
    __syncthreads();
  }
  // epilogue: C row = (lane>>4)*4+reg, col = lane&15  (m89-verified layout)
#pragma unroll
  for (int m = 0; m < 4; ++m) {
    int rbase = mt * 128 + wm * 64 + m * 16 + (lane >> 4) * 4;
#pragma unroll
    for (int n = 0; n < 4; ++n) {
      int v = nt * 128 + wn * 64 + n * 16 + (lane & 15);
      float bv = bias[v];
#pragma unroll
      for (int r = 0; r < 4; ++r) {
        int mi = rbase + r;                  // mi = t*64 + b
        size_t off = (size_t)(mi & 63) * (TT * VV) + (size_t)(mi >> 6) * VV + v;
        out[off] = acc[m][n][r] + bv;
      }
    }
  }
}

extern "C" void kernel_launch(void* const* d_in, const int* in_sizes, int n_in,
                              void* d_out, int out_size, void* d_ws, size_t ws_size,
                              hipStream_t stream) {
  const int*   X     = (const int*)d_in[0];
  const float* enc   = (const float*)d_in[1];
  const float* hs    = (const float*)d_in[2];
  const int*   vlen  = (const int*)d_in[3];
  const float* emb   = (const float*)d_in[4];
  const float* Wq    = (const float*)d_in[5];
  const float* Wk    = (const float*)d_in[6];
  const float* wv    = (const float*)d_in[7];
  const float* W_ih0 = (const float*)d_in[8];
  const float* W_hh0 = (const float*)d_in[9];
  const float* b_ih0 = (const float*)d_in[10];
  const float* b_hh0 = (const float*)d_in[11];
  const float* W_ih1 = (const float*)d_in[12];
  const float* W_hh1 = (const float*)d_in[13];
  const float* b_ih1 = (const float*)d_in[14];
  const float* b_hh1 = (const float*)d_in[15];
  const float* dW    = (const float*)d_in[16];
  const float* db    = (const float*)d_in[17];
  float* out = (float*)d_out;

  char* wp = (char*)d_ws;
  auto alloc = [&](size_t bytes) { char* p = wp; wp += (bytes + 255) & ~(size_t)255; return p; };
  __hip_bfloat16* dWb   = (__hip_bfloat16*)alloc((size_t)VV * HH * 2);
  __hip_bfloat16* outsb = (__hip_bfloat16*)alloc((size_t)TT * BB * HH * 2);
  float* keysp = (float*)alloc((size_t)BB * SS * HH * 4);
  float* gix   = (float*)alloc((size_t)TT * BB * G3 * 4);
  float* WqT   = (float*)alloc((size_t)HH * HH * 4);
  float* WkT   = (float*)alloc((size_t)HH * HH * 4);
  float* WT0   = (float*)alloc((size_t)(HH + EE) * G3 * 4);
  float* WTh0  = (float*)alloc((size_t)HH * G3 * 4);
  float* WT1   = (float*)alloc((size_t)HH * G3 * 4);
  float* WTh1  = (float*)alloc((size_t)HH * G3 * 4);
  float* h0a   = (float*)alloc((size_t)BB * HH * 4);
  float* h0b   = (float*)alloc((size_t)BB * HH * 4);
  float* h1a   = (float*)alloc((size_t)BB * HH * 4);
  float* h1b   = (float*)alloc((size_t)BB * HH * 4);
  float* ctx   = (float*)alloc((size_t)BB * HH * 4);

  dim3 tb(32, 8);
  transpose_kernel<<<dim3(HH / 32, HH / 32), tb, 0, stream>>>(WqT, Wq, HH, HH);
  transpose_kernel<<<dim3(HH / 32, HH / 32), tb, 0, stream>>>(WkT, Wk, HH, HH);
  transpose_kernel<<<dim3((HH + EE) / 32, G3 / 32), tb, 0, stream>>>(WT0, W_ih0, G3, HH + EE);
  transpose_kernel<<<dim3(HH / 32, G3 / 32), tb, 0, stream>>>(WTh0, W_hh0, G3, HH);
  transpose_kernel<<<dim3(HH / 32, G3 / 32), tb, 0, stream>>>(WT1, W_ih1, G3, HH);
  transpose_kernel<<<dim3(HH / 32, G3 / 32), tb, 0, stream>>>(WTh1, W_hh1, G3, HH);
  cast_kernel<<<2048, 256, 0, stream>>>(dW, dWb, VV * HH);
  keys_kernel<<<BB * SS, 256, 0, stream>>>(enc, WkT, keysp);
  gix_kernel<<<TT * BB, 256, 0, stream>>>(X, emb, WT0, b_ih0, gix);

  hipMemcpyAsync(h0a, hs, (size_t)BB * HH * 4, hipMemcpyDeviceToDevice, stream);
  hipMemcpyAsync(h1a, hs + (size_t)BB * HH, (size_t)BB * HH * 4, hipMemcpyDeviceToDevice, stream);

  float* h0buf[2] = {h0a, h0b};
  float* h1buf[2] = {h1a, h1b};
  for (int t = 0; t < TT; ++t) {
    const float* h0i = h0buf[t & 1];
    float* h0o = h0buf[(t + 1) & 1];
    const float* h1i = h1buf[t & 1];
    float* h1o = h1buf[(t + 1) & 1];
    attn_kernel<<<BB, 512, 0, stream>>>(h1i, WqT, keysp, enc, wv, vlen, ctx);
    gru0_kernel<<<256, 256, 0, stream>>>(ctx, h0i, WT0, WTh0, gix, b_hh0, h0o, t);
    gru1_kernel<<<256, 256, 0, stream>>>(h0o, h1i, WT1, WTh1, b_ih1, b_hh1, h1o, outsb, t);
  }
  dense_kernel<<<dim3(32, 250), 256, 0, stream>>>(outsb, dWb, db, out);
}